// Round 12
// baseline (1666.466 us; speedup 1.0000x reference)
//
#include <hip/hip_runtime.h>
#include <stdint.h>

#define NROWS 131072
#define NC 1024
#define ND 512
#define BM 128
#define BN 256
#define NPANEL 4
#define NSTEP 32   // 16 K-steps x {hi, lo} B-tables

using f32x4   = __attribute__((ext_vector_type(4))) float;
using bf16x8  = __attribute__((ext_vector_type(8))) short;
using float4v = __attribute__((ext_vector_type(4))) float;

#define WAITV4() asm volatile("s_waitcnt vmcnt(4)" ::: "memory")
#define WAITV0() asm volatile("s_waitcnt vmcnt(0)" ::: "memory")

__device__ __forceinline__ uint16_t f32_bf16(float f) {
  uint32_t u = __builtin_bit_cast(uint32_t, f);
  u += 0x7FFFu + ((u >> 16) & 1u);   // RNE
  return (uint16_t)(u >> 16);
}
__device__ __forceinline__ float bf16_f32(uint16_t h) {
  uint32_t u = ((uint32_t)h) << 16;
  return __builtin_bit_cast(float, u);
}

__device__ __forceinline__ void gload_lds16(const void* g, void* l) {
  __builtin_amdgcn_global_load_lds(
      (const __attribute__((address_space(1))) unsigned int*)g,
      (__attribute__((address_space(3))) unsigned int*)l, 16, 0, 0);
}

// ---------------------------------------------------------------------------
// Prep centers: bf16 hi/lo, per (panel, kstep) contiguous 16KB block whose
// LINEAR LDS copy yields LDS[c*64 + p*16 + b], p = j ^ ((c>>1)&3) (proven:
// 0 bank conflicts). Also csq[c] in fp32.
// ---------------------------------------------------------------------------
__global__ __launch_bounds__(64) void prep_centers(
    const float* __restrict__ centers,
    uint16_t* __restrict__ cs_hi, uint16_t* __restrict__ cs_lo,
    float* __restrict__ csq) {
  const int c = blockIdx.x;   // 1024
  const int t = threadIdx.x;  // 64
  const float* row = centers + (size_t)c * ND;
  float v[8];
#pragma unroll
  for (int i = 0; i < 8; ++i) v[i] = row[t * 8 + i];
  float ss = 0.f;
#pragma unroll
  for (int i = 0; i < 8; ++i) ss += v[i] * v[i];
#pragma unroll
  for (int m = 1; m < 64; m <<= 1) ss += __shfl_xor(ss, m);
  if (t == 0) csq[c] = ss;

  const int panel = c >> 8;
  const int cw = c & 255;
  const int kk = t >> 2;
  const int j  = t & 3;
  const int p  = j ^ ((cw >> 1) & 3);
  const size_t off = (size_t)(panel * 16 + kk) * 8192 + (size_t)cw * 32 + (size_t)p * 8;
#pragma unroll
  for (int i = 0; i < 8; ++i) {
    uint16_t h = f32_bf16(v[i]);
    uint16_t l = f32_bf16(v[i] - bf16_f32(h));
    cs_hi[off + i] = h;
    cs_lo[off + i] = l;
  }
}

// ---------------------------------------------------------------------------
// Prep x (fully coalesced): block = one rowgroup (128 rows), 512 threads.
// Thread t -> (r = t>>2, q = t&3). Reads: dense 128B lines; writes:
// contiguous 4KB runs per (rg,kk) block, p = q ^ ((r>>1)&3) baked in --
// bit-identical to what kmeans_dist stages linearly + reads conflict-free.
// Also xsq[row] (exact fp32). Scratch lives in prob half of d_out.
// ---------------------------------------------------------------------------
__global__ __launch_bounds__(512) void prep_x(
    const float* __restrict__ x, uint16_t* __restrict__ xh,
    uint16_t* __restrict__ xlo, float* __restrict__ xsq) {
  const int rg = blockIdx.x;        // 0..1023
  const int t  = threadIdx.x;       // 0..511
  const int r  = t >> 2;            // 0..127
  const int q  = t & 3;             // 8-float chunk in 32-k window
  const int row = rg * 128 + r;
  const float* rp = x + (size_t)row * ND + q * 8;
  const int p = q ^ ((r >> 1) & 3);
  const size_t wbase = (size_t)rg * 65536 + (size_t)r * 32 + (size_t)p * 8;
  float ss = 0.f;
#pragma unroll 1
  for (int kk = 0; kk < 16; ++kk) {
    const float* src = rp + kk * 32;
    float4v c0 = *(const float4v*)src;
    float4v c1 = *(const float4v*)(src + 4);
    float v[8] = {c0[0], c0[1], c0[2], c0[3], c1[0], c1[1], c1[2], c1[3]};
    bf16x8 hi, lo;
#pragma unroll
    for (int i = 0; i < 8; ++i) {
      uint16_t hb = f32_bf16(v[i]);
      hi[i] = (short)hb;
      lo[i] = (short)f32_bf16(v[i] - bf16_f32(hb));
      ss += v[i] * v[i];
    }
    *(bf16x8*)(xh  + wbase + (size_t)kk * 4096) = hi;
    *(bf16x8*)(xlo + wbase + (size_t)kk * 4096) = lo;
  }
  ss += __shfl_xor(ss, 1);
  ss += __shfl_xor(ss, 2);
  if (q == 0) xsq[row] = ss;
}

// ---------------------------------------------------------------------------
// Phase 1: distances. 128 rows x 256 cols per block, 512 thr / 8 waves
// (4 wm x 2 wn, wave tile 32x128, acc[2][8] = 64 AGPR). Zero in-loop VALU
// conversion; A and B pre-split bf16, staged linearly via gload_lds
// (4 ops/step), counted vmcnt(4) across raw barriers, proven 0-conflict
// frag swizzle. amdgpu_waves_per_eu(4) caps regs at 128 (64 VGPR + 64 AGPR,
// the round-4-proven no-spill combo) -> 2 blocks/CU. XCD-chunked block
// swizzle: each rg's 4 panel-blocks land consecutively on ONE XCD -> A-tile
// read once (L2-hit for panels 1-3), B tables (2MB) L2-resident per XCD.
// Epilogue: ldsT transpose (unions loop smem) -> contiguous float4 stores.
// ---------------------------------------------------------------------------
__global__ __launch_bounds__(512)
__attribute__((amdgpu_waves_per_eu(4)))
void kmeans_dist(
    const float* __restrict__ xsq_g,
    const uint16_t* __restrict__ xh, const uint16_t* __restrict__ xlo,
    const uint16_t* __restrict__ cs_hi, const uint16_t* __restrict__ cs_lo,
    const float* __restrict__ csq,
    float* __restrict__ dist) {
  // bs dbuf @0/16384 (16KB each); ahi dbuf @32768 (8KB each); alo dbuf @49152.
  __shared__ __align__(16) char smem[65536];

  const int tid  = threadIdx.x;
  const int lane = tid & 63;
  const int wid  = tid >> 6;        // 0..7
  const int wm   = wid >> 1;        // 0..3 -> rows wm*32
  const int wn   = wid & 1;         // 0..1 -> cols wn*128
  // XCD-chunked swizzle (bijective: 4096 % 8 == 0): 512 consecutive bids/XCD
  const int bid  = (blockIdx.x & 7) * 512 + (blockIdx.x >> 3);
  const int rg   = bid >> 2;        // row group (128 rows)
  const int panel = bid & 3;        // 256-col panel
  const int row0 = rg * BM;
  const int arow = lane & 15;
  const int kq   = lane >> 4;

  auto stageB = [&](int s) {
    const uint16_t* base = (s < 16) ? cs_hi : cs_lo;
    const char* srcb = (const char*)(base + (size_t)(panel * 16 + (s & 15)) * 8192);
    char* dst = smem + (s & 1) * 16384;
    const int o = tid * 16;
    gload_lds16(srcb + o, dst + o);
    gload_lds16(srcb + o + 8192, dst + o + 8192);
  };
  auto stageA = [&](int s) {
    const size_t off = (size_t)(rg * 16 + (s & 15)) * 8192 + tid * 16;
    gload_lds16((const char*)xh + off,  smem + 32768 + (s & 1) * 8192 + tid * 16);
    gload_lds16((const char*)xlo + off, smem + 49152 + (s & 1) * 8192 + tid * 16);
  };

  f32x4 acc[2][8];
  const f32x4 z = {0.f, 0.f, 0.f, 0.f};
#pragma unroll
  for (int mr = 0; mr < 2; ++mr)
#pragma unroll
    for (int n = 0; n < 8; ++n) acc[mr][n] = z;

  const int swz  = ((kq ^ ((arow >> 1) & 3)) << 4);
  const int boff = (wn * 128 + arow) * 64 + swz;   // + n*1024
  const int aoff = (wm * 32 + arow) * 64 + swz;    // + mr*1024

  // ---- prologue: batch 0 in flight (2 B + 2 A) ----
  stageB(0);
  stageA(0);

#pragma unroll 1
  for (int s = 0; s < NSTEP; ++s) {
    if (s + 1 < NSTEP) {
      stageB(s + 1);
      stageA(s + 1);
      WAITV4();                     // batch s (4 oldest) complete
    } else {
      WAITV0();
    }
    __builtin_amdgcn_s_barrier();   // stage(s) visible to all waves

    {
      const char* bp  = smem + (s & 1) * 16384;
      const char* ahp = smem + 32768 + (s & 1) * 8192;
      bf16x8 ah0 = *(const bf16x8*)(ahp + aoff);
      bf16x8 ah1 = *(const bf16x8*)(ahp + aoff + 1024);
      __builtin_amdgcn_s_setprio(1);
      if (s < 16) {
        const char* alp = smem + 49152 + (s & 1) * 8192;
        bf16x8 al0 = *(const bf16x8*)(alp + aoff);
        bf16x8 al1 = *(const bf16x8*)(alp + aoff + 1024);
#pragma unroll
        for (int n = 0; n < 4; ++n) {
          bf16x8 b = *(const bf16x8*)(bp + boff + n * 1024);
          acc[0][n] = __builtin_amdgcn_mfma_f32_16x16x32_bf16(ah0, b, acc[0][n], 0, 0, 0);
          acc[1][n] = __builtin_amdgcn_mfma_f32_16x16x32_bf16(ah1, b, acc[1][n], 0, 0, 0);
          acc[0][n] = __builtin_amdgcn_mfma_f32_16x16x32_bf16(al0, b, acc[0][n], 0, 0, 0);
          acc[1][n] = __builtin_amdgcn_mfma_f32_16x16x32_bf16(al1, b, acc[1][n], 0, 0, 0);
        }
        __builtin_amdgcn_sched_barrier(0);   // cap live b-frags at 4
#pragma unroll
        for (int n = 4; n < 8; ++n) {
          bf16x8 b = *(const bf16x8*)(bp + boff + n * 1024);
          acc[0][n] = __builtin_amdgcn_mfma_f32_16x16x32_bf16(ah0, b, acc[0][n], 0, 0, 0);
          acc[1][n] = __builtin_amdgcn_mfma_f32_16x16x32_bf16(ah1, b, acc[1][n], 0, 0, 0);
          acc[0][n] = __builtin_amdgcn_mfma_f32_16x16x32_bf16(al0, b, acc[0][n], 0, 0, 0);
          acc[1][n] = __builtin_amdgcn_mfma_f32_16x16x32_bf16(al1, b, acc[1][n], 0, 0, 0);
        }
      } else {
#pragma unroll
        for (int n = 0; n < 4; ++n) {
          bf16x8 b = *(const bf16x8*)(bp + boff + n * 1024);
          acc[0][n] = __builtin_amdgcn_mfma_f32_16x16x32_bf16(ah0, b, acc[0][n], 0, 0, 0);
          acc[1][n] = __builtin_amdgcn_mfma_f32_16x16x32_bf16(ah1, b, acc[1][n], 0, 0, 0);
        }
        __builtin_amdgcn_sched_barrier(0);
#pragma unroll
        for (int n = 4; n < 8; ++n) {
          bf16x8 b = *(const bf16x8*)(bp + boff + n * 1024);
          acc[0][n] = __builtin_amdgcn_mfma_f32_16x16x32_bf16(ah0, b, acc[0][n], 0, 0, 0);
          acc[1][n] = __builtin_amdgcn_mfma_f32_16x16x32_bf16(ah1, b, acc[1][n], 0, 0, 0);
        }
      }
      __builtin_amdgcn_s_setprio(0);
    }
    __builtin_amdgcn_s_barrier();   // reads done before next overwrite
  }

  // csq for this panel (one float4 per lane)
  const float4v cq = *(const float4v*)(csq + panel * BN + lane * 4);

  // ---- epilogue: 4 transpose passes (32 rows each), contiguous stores ----
  float* ldsT = (float*)smem;   // 32 x 258 fp32 = 33KB (unions over loop smem)
  const int rsub = (lane >> 4) * 4;
#pragma unroll
  for (int g = 0; g < 4; ++g) {
    if (wm == g) {
#pragma unroll
      for (int mr = 0; mr < 2; ++mr)
#pragma unroll
        for (int n = 0; n < 8; ++n)
#pragma unroll
          for (int rr = 0; rr < 4; ++rr)
            ldsT[(mr * 16 + rsub + rr) * 258 + wn * 128 + n * 16 + arow] = acc[mr][n][rr];
    }
    __syncthreads();
    {
      const int lr = wid * 4;     // 4 rows per wave
#pragma unroll
      for (int q = 0; q < 4; ++q) {
        const int r = lr + q;
        const float xq = xsq_g[row0 + g * 32 + r];
        const float4v raw = *(const float4v*)&ldsT[r * 258 + lane * 4];
        float4v dd;
#pragma unroll
        for (int i = 0; i < 4; ++i)
          dd[i] = fmaxf(xq + cq[i] - 2.0f * raw[i], 0.0f);
        *(float4v*)(dist + (size_t)(row0 + g * 32 + r) * NC + panel * BN + lane * 4) = dd;
      }
    }
    __syncthreads();
  }
}

// ---------------------------------------------------------------------------
// Phase 2: row softmax(-dist) -> prob. One wave per row, contiguous float4.
// ---------------------------------------------------------------------------
__global__ __launch_bounds__(512) void softmax_rows(
    const float* __restrict__ dist, float* __restrict__ prob) {
  const int tid  = threadIdx.x;
  const int lane = tid & 63;
  const int wid  = tid >> 6;
  const size_t row = (size_t)blockIdx.x * 8 + wid;
  const float* dp = dist + row * NC;
  float* pp = prob + row * NC;

  float4v dd[4];
#pragma unroll
  for (int j = 0; j < 4; ++j)
    dd[j] = *(const float4v*)(dp + lane * 4 + j * 256);

  float dmin = 1e30f;
#pragma unroll
  for (int j = 0; j < 4; ++j)
#pragma unroll
    for (int i = 0; i < 4; ++i) dmin = fminf(dmin, dd[j][i]);
#pragma unroll
  for (int m = 1; m < 64; m <<= 1) dmin = fminf(dmin, __shfl_xor(dmin, m));

  float ssum = 0.f;
#pragma unroll
  for (int j = 0; j < 4; ++j)
#pragma unroll
    for (int i = 0; i < 4; ++i) {
      float e = __expf(dmin - dd[j][i]);
      dd[j][i] = e;
      ssum += e;
    }
#pragma unroll
  for (int m = 1; m < 64; m <<= 1) ssum += __shfl_xor(ssum, m);
  const float sinv = 1.0f / ssum;

#pragma unroll
  for (int j = 0; j < 4; ++j) {
    float4v pv;
#pragma unroll
    for (int i = 0; i < 4; ++i) pv[i] = dd[j][i] * sinv;
    *(float4v*)(pp + lane * 4 + j * 256) = pv;
  }
}

extern "C" void kernel_launch(void* const* d_in, const int* in_sizes, int n_in,
                              void* d_out, int out_size, void* d_ws, size_t ws_size,
                              hipStream_t stream) {
  const float* x = (const float*)d_in[0];
  const float* centers = (const float*)d_in[1];
  float* dist = (float*)d_out;
  float* prob = dist + (size_t)NROWS * NC;

  // x_hi/x_lo/xsq scratch lives in the prob half of d_out (536MB): written by
  // prep_x, consumed by kmeans_dist, then fully overwritten by softmax_rows.
  uint16_t* xh  = (uint16_t*)prob;                       // 134 MB
  uint16_t* xlo = xh + (size_t)NROWS * ND;               // 134 MB
  float* xsq    = (float*)(xlo + (size_t)NROWS * ND);    // 512 KB

  uint16_t* cs_hi = (uint16_t*)d_ws;                     // 1 MB
  uint16_t* cs_lo = cs_hi + (size_t)NC * ND;             // 1 MB
  float* csq = (float*)(cs_lo + (size_t)NC * ND);        // 4 KB

  prep_centers<<<dim3(NC), dim3(64), 0, stream>>>(centers, cs_hi, cs_lo, csq);
  prep_x<<<dim3(NROWS / 128), dim3(512), 0, stream>>>(x, xh, xlo, xsq);
  kmeans_dist<<<dim3((NROWS / BM) * NPANEL), dim3(512), 0, stream>>>(
      xsq, xh, xlo, cs_hi, cs_lo, csq, dist);
  softmax_rows<<<dim3(NROWS / 8), dim3(512), 0, stream>>>(dist, prob);
}